// Round 4
// baseline (378.074 us; speedup 1.0000x reference)
//
#include <hip/hip_runtime.h>
#include <hip/hip_cooperative_groups.h>

namespace cg = cooperative_groups;

#define IN_DIM 128
#define NB 5
#define PB_NODES 128      // nodes per proj block-iteration
#define GRID_BLOCKS 1024  // 4 blocks/CU x 256 CUs (co-resident for cooperative)
#define TPB 256

// ---------------------------------------------------------------------------
// scoring math shared by fused + fallback kernels
// ---------------------------------------------------------------------------
__device__ __forceinline__ float edge_score(
    float4 a0, float4 a1, float4 c0, float4 c1,
    float b0, float b1, float b2, float b3, float b4,
    float s0, float s1, float s2, float s3, float s4, float sb)
{
    float l0 = a0.x + c0.x + b0;
    float l1 = a0.y + c0.y + b1;
    float l2 = a0.z + c0.z + b2;
    float l3 = a0.w + c0.w + b3;
    float l4 = a1.x + c1.x + b4;
    float lsc = a1.y + c1.y;            // edge_feats . scorer_w
    float m = fmaxf(fmaxf(fmaxf(l0, l1), fmaxf(l2, l3)), l4);
    float e0 = __expf(l0 - m);
    float e1 = __expf(l1 - m);
    float e2 = __expf(l2 - m);
    float e3 = __expf(l3 - m);
    float e4 = __expf(l4 - m);
    float inv = 1.f / (e0 + e1 + e2 + e3 + e4);
    float mix = (e0 * s0 + e1 * s1 + e2 * s2 + e3 * s3 + e4 * s4) * inv;
    float logit = lsc + mix + sb;
    return 1.f / (1.f + __expf(-logit));
}

// ---------------------------------------------------------------------------
// FUSED cooperative kernel: phase A (prep + proj) -> grid.sync -> phase B edges
// ---------------------------------------------------------------------------
__global__ __launch_bounds__(TPB, 4) void fused_kernel(
    const float* __restrict__ x,          // [N][128]
    const float* __restrict__ attn_w,     // [5][256]
    const float* __restrict__ scorer_w,   // [256]
    const float* __restrict__ bases,      // [5][256]
    const int*   __restrict__ eidx,       // index buffer viewed as int32
    const float* __restrict__ attn_b,     // [5]
    const float* __restrict__ scorer_b,   // [1]
    const float* __restrict__ ew,         // [E]
    float* srcTab,                        // [N][8]  (ws)
    float* dstTab,                        // [N][8]  (ws)
    float* bs,                            // [5]     (ws)
    int*   flag,                          // [1]     (ws)
    float* __restrict__ out,              // [E]
    int n_nodes, int n_edges)
{
    const int t = threadIdx.x;
    const int lane = t & 63;
    __shared__ float red[4][PB_NODES][13];
    __shared__ float part_s[4][NB];

    // ================= Phase A =================
    if (blockIdx.x == gridDim.x - 1) {
        // ---- prep: bs[k] = dot(bases[k], scorer_w); index-width probe ----
        float p[NB];
        #pragma unroll
        for (int k = 0; k < NB; ++k)
            p[k] = bases[k * 256 + t] * scorer_w[t];
        #pragma unroll
        for (int k = 0; k < NB; ++k) {
            #pragma unroll
            for (int off = 32; off > 0; off >>= 1)
                p[k] += __shfl_xor(p[k], off, 64);
        }
        const int w = t >> 6, l = t & 63;
        if (l == 0) {
            #pragma unroll
            for (int k = 0; k < NB; ++k) part_s[w][k] = p[k];
        }
        __syncthreads();
        if (t < NB) bs[t] = part_s[0][t] + part_s[1][t] + part_s[2][t] + part_s[3][t];
        if (w == 1) {
            int v = eidx[2 * l + 1];  // odd dwords of first 64 int64 slots
            unsigned long long any = __ballot(v != 0);
            if (l == 0) *flag = any ? 1 : 2;
        }
    } else {
        // ---- proj: block-iteration b covers nodes [b*128, b*128+128) ----
        const int part = __builtin_amdgcn_readfirstlane(t >> 6);  // wave-uniform 0..3
        const float* wbp[12] = {
            attn_w + 0 * 256 + part * 32, attn_w + 1 * 256 + part * 32,
            attn_w + 2 * 256 + part * 32, attn_w + 3 * 256 + part * 32,
            attn_w + 4 * 256 + part * 32, scorer_w + part * 32,
            attn_w + 0 * 256 + 128 + part * 32, attn_w + 1 * 256 + 128 + part * 32,
            attn_w + 2 * 256 + 128 + part * 32, attn_w + 3 * 256 + 128 + part * 32,
            attn_w + 4 * 256 + 128 + part * 32, scorer_w + 128 + part * 32};

        const int nPB = (n_nodes + PB_NODES - 1) / PB_NODES;
        for (int b = blockIdx.x; b < nPB; b += gridDim.x - 1) {
            const int n0 = b * PB_NODES + lane;        // first node of this lane
            const int n1 = n0 + 64;                    // second node
            const bool v0 = n0 < n_nodes, v1 = n1 < n_nodes;

            float acc0[12], acc1[12];
            #pragma unroll
            for (int j = 0; j < 12; ++j) { acc0[j] = 0.f; acc1[j] = 0.f; }

            // pre-issue 16 independent float4 x-loads (clamped addresses)
            const float4* xr0 = (const float4*)(x + (size_t)(v0 ? n0 : 0) * IN_DIM + part * 32);
            const float4* xr1 = (const float4*)(x + (size_t)(v1 ? n1 : 0) * IN_DIM + part * 32);
            float4 xv0[8], xv1[8];
            #pragma unroll
            for (int q = 0; q < 8; ++q) xv0[q] = xr0[q];
            #pragma unroll
            for (int q = 0; q < 8; ++q) xv1[q] = xr1[q];

            #pragma unroll
            for (int q = 0; q < 8; ++q) {
                #pragma unroll
                for (int j = 0; j < 12; ++j) {
                    float4 wv = *(const float4*)(wbp[j] + q * 4);  // uniform -> s_load
                    acc0[j] = fmaf(xv0[q].x, wv.x, fmaf(xv0[q].y, wv.y,
                              fmaf(xv0[q].z, wv.z, fmaf(xv0[q].w, wv.w, acc0[j]))));
                    acc1[j] = fmaf(xv1[q].x, wv.x, fmaf(xv1[q].y, wv.y,
                              fmaf(xv1[q].z, wv.z, fmaf(xv1[q].w, wv.w, acc1[j]))));
                }
            }

            #pragma unroll
            for (int j = 0; j < 12; ++j) {
                red[part][lane][j]      = v0 ? acc0[j] : 0.f;
                red[part][64 + lane][j] = v1 ? acc1[j] : 0.f;
            }
            __syncthreads();

            // 128 nodes x 12 outputs = 1536 sums; 6 per thread
            #pragma unroll
            for (int k = 0; k < 6; ++k) {
                int s = t + k * TPB;
                int node = s / 12, j = s - node * 12;
                float v = red[0][node][j] + red[1][node][j] +
                          red[2][node][j] + red[3][node][j];
                int nn = b * PB_NODES + node;
                if (nn < n_nodes) {
                    if (j < 6) srcTab[(size_t)nn * 8 + j]       = v;
                    else       dstTab[(size_t)nn * 8 + (j - 6)] = v;
                }
            }
            __syncthreads();
        }
    }

    __threadfence();            // release: make table/bs/flag visible device-wide
    cg::this_grid().sync();
    __threadfence();            // acquire: don't serve stale L1/L2

    // ================= Phase B: edges, 4 per thread =================
    const int stride = *flag;
    const float b0 = attn_b[0], b1 = attn_b[1], b2 = attn_b[2],
                b3 = attn_b[3], b4 = attn_b[4];
    const float sb = scorer_b[0];
    const float s0 = bs[0], s1 = bs[1], s2 = bs[2], s3 = bs[3], s4 = bs[4];
    const bool vecOK = ((n_edges & 3) == 0);

    const int tot = gridDim.x * TPB * 4;
    for (int e0 = (blockIdx.x * TPB + t) * 4; e0 < n_edges; e0 += tot) {
        int si[4], di[4];
        const bool full = (e0 + 3 < n_edges);
        if (full && vecOK) {
            if (stride == 2) {
                int4 A = *(const int4*)(eidx + 2 * (size_t)e0);
                int4 B = *(const int4*)(eidx + 2 * (size_t)e0 + 4);
                int4 C = *(const int4*)(eidx + 2 * ((size_t)n_edges + e0));
                int4 D = *(const int4*)(eidx + 2 * ((size_t)n_edges + e0) + 4);
                si[0] = A.x; si[1] = A.z; si[2] = B.x; si[3] = B.z;
                di[0] = C.x; di[1] = C.z; di[2] = D.x; di[3] = D.z;
            } else {
                int4 A = *(const int4*)(eidx + e0);
                int4 C = *(const int4*)(eidx + (size_t)n_edges + e0);
                si[0] = A.x; si[1] = A.y; si[2] = A.z; si[3] = A.w;
                di[0] = C.x; di[1] = C.y; di[2] = C.z; di[3] = C.w;
            }
            // issue all 16 row loads before any compute
            const float4* ps0 = (const float4*)(srcTab + (size_t)si[0] * 8);
            const float4* ps1 = (const float4*)(srcTab + (size_t)si[1] * 8);
            const float4* ps2 = (const float4*)(srcTab + (size_t)si[2] * 8);
            const float4* ps3 = (const float4*)(srcTab + (size_t)si[3] * 8);
            const float4* pd0 = (const float4*)(dstTab + (size_t)di[0] * 8);
            const float4* pd1 = (const float4*)(dstTab + (size_t)di[1] * 8);
            const float4* pd2 = (const float4*)(dstTab + (size_t)di[2] * 8);
            const float4* pd3 = (const float4*)(dstTab + (size_t)di[3] * 8);
            float4 a00 = ps0[0], a01 = ps0[1];
            float4 a10 = ps1[0], a11 = ps1[1];
            float4 a20 = ps2[0], a21 = ps2[1];
            float4 a30 = ps3[0], a31 = ps3[1];
            float4 c00 = pd0[0], c01 = pd0[1];
            float4 c10 = pd1[0], c11 = pd1[1];
            float4 c20 = pd2[0], c21 = pd2[1];
            float4 c30 = pd3[0], c31 = pd3[1];
            float4 wv = *(const float4*)(ew + e0);

            float r0 = wv.x * edge_score(a00, a01, c00, c01, b0,b1,b2,b3,b4, s0,s1,s2,s3,s4, sb);
            float r1 = wv.y * edge_score(a10, a11, c10, c11, b0,b1,b2,b3,b4, s0,s1,s2,s3,s4, sb);
            float r2 = wv.z * edge_score(a20, a21, c20, c21, b0,b1,b2,b3,b4, s0,s1,s2,s3,s4, sb);
            float r3 = wv.w * edge_score(a30, a31, c30, c31, b0,b1,b2,b3,b4, s0,s1,s2,s3,s4, sb);
            *(float4*)(out + e0) = make_float4(r0, r1, r2, r3);
        } else {
            for (int k = 0; k < 4; ++k) {
                int e = e0 + k;
                if (e >= n_edges) break;
                int src, dst;
                if (stride == 2) {
                    src = eidx[2 * (size_t)e];
                    dst = eidx[2 * ((size_t)n_edges + e)];
                } else {
                    src = eidx[e];
                    dst = eidx[(size_t)n_edges + e];
                }
                const float4* ps = (const float4*)(srcTab + (size_t)src * 8);
                const float4* pd = (const float4*)(dstTab + (size_t)dst * 8);
                float4 a0 = ps[0], a1 = ps[1], c0 = pd[0], c1 = pd[1];
                out[e] = ew[e] * edge_score(a0, a1, c0, c1,
                                            b0,b1,b2,b3,b4, s0,s1,s2,s3,s4, sb);
            }
        }
    }
}

// ---------------------------------------------------------------------------
// FALLBACK kernels (non-cooperative), in case cooperative capture fails
// ---------------------------------------------------------------------------
__global__ __launch_bounds__(256) void proj_prep_kernel(
    const float* __restrict__ x, const float* __restrict__ attn_w,
    const float* __restrict__ scorer_w, const float* __restrict__ bases,
    const int* __restrict__ eidx, float* __restrict__ srcTab,
    float* __restrict__ dstTab, float* __restrict__ bs,
    int* __restrict__ flag, int n_nodes)
{
    const int t = threadIdx.x;
    if (blockIdx.x == gridDim.x - 1) {
        float p[NB];
        #pragma unroll
        for (int k = 0; k < NB; ++k)
            p[k] = bases[k * 256 + t] * scorer_w[t];
        #pragma unroll
        for (int k = 0; k < NB; ++k) {
            #pragma unroll
            for (int off = 32; off > 0; off >>= 1)
                p[k] += __shfl_xor(p[k], off, 64);
        }
        __shared__ float part_s[4][NB];
        const int w = t >> 6, l = t & 63;
        if (l == 0) {
            #pragma unroll
            for (int k = 0; k < NB; ++k) part_s[w][k] = p[k];
        }
        __syncthreads();
        if (t < NB) bs[t] = part_s[0][t] + part_s[1][t] + part_s[2][t] + part_s[3][t];
        if (w == 1) {
            int v = eidx[2 * l + 1];
            unsigned long long any = __ballot(v != 0);
            if (l == 0) *flag = any ? 1 : 2;
        }
        return;
    }
    const int lane = t & 63;
    const int part = __builtin_amdgcn_readfirstlane(t >> 6);
    const int n = blockIdx.x * 64 + lane;
    const float* wbp[12] = {
        attn_w + 0 * 256 + part * 32, attn_w + 1 * 256 + part * 32,
        attn_w + 2 * 256 + part * 32, attn_w + 3 * 256 + part * 32,
        attn_w + 4 * 256 + part * 32, scorer_w + part * 32,
        attn_w + 0 * 256 + 128 + part * 32, attn_w + 1 * 256 + 128 + part * 32,
        attn_w + 2 * 256 + 128 + part * 32, attn_w + 3 * 256 + 128 + part * 32,
        attn_w + 4 * 256 + 128 + part * 32, scorer_w + 128 + part * 32};
    float acc[12];
    #pragma unroll
    for (int j = 0; j < 12; ++j) acc[j] = 0.f;
    if (n < n_nodes) {
        const float4* xr = (const float4*)(x + (size_t)n * IN_DIM + part * 32);
        float4 xv[8];
        #pragma unroll
        for (int q = 0; q < 8; ++q) xv[q] = xr[q];
        #pragma unroll
        for (int q = 0; q < 8; ++q) {
            #pragma unroll
            for (int j = 0; j < 12; ++j) {
                float4 wv = *(const float4*)(wbp[j] + q * 4);
                acc[j] = fmaf(xv[q].x, wv.x, fmaf(xv[q].y, wv.y,
                         fmaf(xv[q].z, wv.z, fmaf(xv[q].w, wv.w, acc[j]))));
            }
        }
    }
    __shared__ float red[4][64][13];
    #pragma unroll
    for (int j = 0; j < 12; ++j) red[part][lane][j] = acc[j];
    __syncthreads();
    #pragma unroll
    for (int k = 0; k < 3; ++k) {
        int s = t + k * 256;
        int node = s / 12, j = s - node * 12;
        float v = red[0][node][j] + red[1][node][j] + red[2][node][j] + red[3][node][j];
        int nn = blockIdx.x * 64 + node;
        if (nn < n_nodes) {
            if (j < 6) srcTab[(size_t)nn * 8 + j]       = v;
            else       dstTab[(size_t)nn * 8 + (j - 6)] = v;
        }
    }
}

__global__ __launch_bounds__(256) void edge_kernel(
    const int* __restrict__ eidx, const float* __restrict__ ew,
    const float* __restrict__ attn_b, const float* __restrict__ scorer_b,
    const float* __restrict__ srcTab, const float* __restrict__ dstTab,
    const float* __restrict__ bs, const int* __restrict__ flag,
    float* __restrict__ out, int n_edges)
{
    const int e = blockIdx.x * 256 + threadIdx.x;
    if (e >= n_edges) return;
    const int stride = *flag;
    int src, dst;
    if (stride == 2) {
        src = eidx[2 * (size_t)e];
        dst = eidx[2 * ((size_t)n_edges + e)];
    } else {
        src = eidx[e];
        dst = eidx[(size_t)n_edges + e];
    }
    const float4* ps = (const float4*)(srcTab + (size_t)src * 8);
    const float4* pd = (const float4*)(dstTab + (size_t)dst * 8);
    float4 a0 = ps[0], a1 = ps[1], c0 = pd[0], c1 = pd[1];
    float w = ew[e];
    out[e] = w * edge_score(a0, a1, c0, c1,
                            attn_b[0], attn_b[1], attn_b[2], attn_b[3], attn_b[4],
                            bs[0], bs[1], bs[2], bs[3], bs[4], scorer_b[0]);
}

// ---------------------------------------------------------------------------
extern "C" void kernel_launch(void* const* d_in, const int* in_sizes, int n_in,
                              void* d_out, int out_size, void* d_ws, size_t ws_size,
                              hipStream_t stream) {
    const float* x        = (const float*)d_in[0];
    const int*   eidx     = (const int*)  d_in[1];
    const float* ew       = (const float*)d_in[2];
    const float* bases    = (const float*)d_in[3];
    const float* attn_w   = (const float*)d_in[4];
    const float* attn_b   = (const float*)d_in[5];
    const float* scorer_w = (const float*)d_in[6];
    const float* scorer_b = (const float*)d_in[7];
    float* out = (float*)d_out;

    int n_nodes = in_sizes[0] / IN_DIM;
    int n_edges = in_sizes[2];

    int*   flag   = (int*)d_ws;
    float* bs     = (float*)d_ws + 16;
    float* srcTab = (float*)d_ws + 64;
    float* dstTab = srcTab + (size_t)n_nodes * 8;

    void* args[] = {
        (void*)&x, (void*)&attn_w, (void*)&scorer_w, (void*)&bases,
        (void*)&eidx, (void*)&attn_b, (void*)&scorer_b, (void*)&ew,
        (void*)&srcTab, (void*)&dstTab, (void*)&bs, (void*)&flag,
        (void*)&out, (void*)&n_nodes, (void*)&n_edges};

    hipError_t err = hipLaunchCooperativeKernel(
        (const void*)fused_kernel, dim3(GRID_BLOCKS), dim3(TPB),
        args, 0, stream);

    if (err != hipSuccess) {
        // non-cooperative fallback: two kernels
        const int pblocks = (n_nodes + 63) / 64;
        proj_prep_kernel<<<pblocks + 1, 256, 0, stream>>>(
            x, attn_w, scorer_w, bases, eidx, srcTab, dstTab, bs, flag, n_nodes);
        const int eblocks = (n_edges + 255) / 256;
        edge_kernel<<<eblocks, 256, 0, stream>>>(
            eidx, ew, attn_b, scorer_b, srcTab, dstTab, bs, flag, out, n_edges);
    }
}

// Round 5
// 107.040 us; speedup vs baseline: 3.5321x; 3.5321x over previous
//
#include <hip/hip_runtime.h>

#define IN_DIM 128
#define NB 5

// ---------------------------------------------------------------------------
// shared edge-scoring math
// ---------------------------------------------------------------------------
__device__ __forceinline__ float edge_score(
    float4 a0, float4 a1, float4 c0, float4 c1,
    float b0, float b1, float b2, float b3, float b4,
    float s0, float s1, float s2, float s3, float s4, float sb)
{
    float l0 = a0.x + c0.x + b0;
    float l1 = a0.y + c0.y + b1;
    float l2 = a0.z + c0.z + b2;
    float l3 = a0.w + c0.w + b3;
    float l4 = a1.x + c1.x + b4;
    float lsc = a1.y + c1.y;            // edge_feats . scorer_w
    float m = fmaxf(fmaxf(fmaxf(l0, l1), fmaxf(l2, l3)), l4);
    float e0 = __expf(l0 - m);
    float e1 = __expf(l1 - m);
    float e2 = __expf(l2 - m);
    float e3 = __expf(l3 - m);
    float e4 = __expf(l4 - m);
    float inv = 1.f / (e0 + e1 + e2 + e3 + e4);
    float mix = (e0 * s0 + e1 * s1 + e2 * s2 + e3 * s3 + e4 * s4) * inv;
    float logit = lsc + mix + sb;
    return 1.f / (1.f + __expf(-logit));
}

// ---------------------------------------------------------------------------
// K1: per-node projection tables (+ basis scores + index-width probe).
//   srcTab[n][0..4] = x[n].attn_w[k][0:128],   [5] = x[n].scorer_w[0:128]
//   dstTab[n][0..4] = x[n].attn_w[k][128:256], [5] = x[n].scorer_w[128:256]
// Rows 32 B (8 floats; slots 6,7 pad).
// Block = 256 thr = 4 waves, covers 128 nodes: wave w owns dim-quarter w,
// lane l owns nodes (b*128+l) and (b*128+64+l) -> 16 independent float4
// x-loads in flight per thread. Weight addresses wave-uniform -> s_load.
// Cross-wave reduce via padded LDS. Last block: bs[] + int64/int32 probe.
// ---------------------------------------------------------------------------
__global__ __launch_bounds__(256) void proj_prep_kernel(
    const float* __restrict__ x,          // [N][128]
    const float* __restrict__ attn_w,     // [5][256]
    const float* __restrict__ scorer_w,   // [256]
    const float* __restrict__ bases,      // [5][256]
    const int*   __restrict__ eidx,       // index buffer viewed as int32
    float* __restrict__ srcTab,           // [N][8]
    float* __restrict__ dstTab,           // [N][8]
    float* __restrict__ bs,               // [5]
    int*   __restrict__ flag,             // stride (1 or 2)
    int n_nodes)
{
    const int t = threadIdx.x;

    if (blockIdx.x == gridDim.x - 1) {
        // ---- prep block ----
        float p[NB];
        #pragma unroll
        for (int k = 0; k < NB; ++k)
            p[k] = bases[k * 256 + t] * scorer_w[t];
        #pragma unroll
        for (int k = 0; k < NB; ++k) {
            #pragma unroll
            for (int off = 32; off > 0; off >>= 1)
                p[k] += __shfl_xor(p[k], off, 64);
        }
        __shared__ float part_s[4][NB];
        const int w = t >> 6, l = t & 63;
        if (l == 0) {
            #pragma unroll
            for (int k = 0; k < NB; ++k) part_s[w][k] = p[k];
        }
        __syncthreads();
        if (t < NB) bs[t] = part_s[0][t] + part_s[1][t] + part_s[2][t] + part_s[3][t];

        if (w == 1) {
            int v = eidx[2 * l + 1];   // odd dwords of first 64 int64 slots
            unsigned long long any = __ballot(v != 0);
            if (l == 0) *flag = any ? 1 : 2;
        }
        return;
    }

    const int lane = t & 63;
    const int part = __builtin_amdgcn_readfirstlane(t >> 6);   // 0..3 wave-uniform

    const float* __restrict__ wbp[12] = {
        attn_w + 0 * 256 + part * 32, attn_w + 1 * 256 + part * 32,
        attn_w + 2 * 256 + part * 32, attn_w + 3 * 256 + part * 32,
        attn_w + 4 * 256 + part * 32, scorer_w + part * 32,
        attn_w + 0 * 256 + 128 + part * 32, attn_w + 1 * 256 + 128 + part * 32,
        attn_w + 2 * 256 + 128 + part * 32, attn_w + 3 * 256 + 128 + part * 32,
        attn_w + 4 * 256 + 128 + part * 32, scorer_w + 128 + part * 32};

    const int n0 = blockIdx.x * 128 + lane;
    const int n1 = n0 + 64;
    const bool v0 = n0 < n_nodes, v1 = n1 < n_nodes;

    float acc0[12], acc1[12];
    #pragma unroll
    for (int j = 0; j < 12; ++j) { acc0[j] = 0.f; acc1[j] = 0.f; }

    // pre-issue 16 independent float4 x-loads (clamped addresses)
    const float4* __restrict__ xr0 =
        (const float4*)(x + (size_t)(v0 ? n0 : 0) * IN_DIM + part * 32);
    const float4* __restrict__ xr1 =
        (const float4*)(x + (size_t)(v1 ? n1 : 0) * IN_DIM + part * 32);
    float4 xv0[8], xv1[8];
    #pragma unroll
    for (int q = 0; q < 8; ++q) xv0[q] = xr0[q];
    #pragma unroll
    for (int q = 0; q < 8; ++q) xv1[q] = xr1[q];

    #pragma unroll
    for (int q = 0; q < 8; ++q) {
        #pragma unroll
        for (int j = 0; j < 12; ++j) {
            float4 wv = *(const float4*)(wbp[j] + q * 4);   // uniform -> s_load
            acc0[j] = fmaf(xv0[q].x, wv.x, fmaf(xv0[q].y, wv.y,
                      fmaf(xv0[q].z, wv.z, fmaf(xv0[q].w, wv.w, acc0[j]))));
            acc1[j] = fmaf(xv1[q].x, wv.x, fmaf(xv1[q].y, wv.y,
                      fmaf(xv1[q].z, wv.z, fmaf(xv1[q].w, wv.w, acc1[j]))));
        }
    }

    // cross-wave reduce: [part][node][j], inner dim 13 (odd -> conflict-free)
    __shared__ float red[4][128][13];
    #pragma unroll
    for (int j = 0; j < 12; ++j) {
        red[part][lane][j]      = acc0[j];
        red[part][64 + lane][j] = acc1[j];
    }
    __syncthreads();

    // 128 nodes x 12 outputs = 1536 sums; 6 per thread
    #pragma unroll
    for (int k = 0; k < 6; ++k) {
        int s = t + k * 256;
        int node = s / 12, j = s - node * 12;
        float v = red[0][node][j] + red[1][node][j] +
                  red[2][node][j] + red[3][node][j];
        int nn = blockIdx.x * 128 + node;
        if (nn < n_nodes) {
            if (j < 6) srcTab[(size_t)nn * 8 + j]       = v;
            else       dstTab[(size_t)nn * 8 + (j - 6)] = v;
        }
    }
}

// ---------------------------------------------------------------------------
// K2: per-edge attention + scorer, 1 edge/thread (max TLP, min VGPR)
// ---------------------------------------------------------------------------
__global__ __launch_bounds__(256) void edge_kernel(
    const int*   __restrict__ eidx,
    const float* __restrict__ ew,
    const float* __restrict__ attn_b,     // [5]
    const float* __restrict__ scorer_b,   // [1]
    const float* __restrict__ srcTab,     // [N][8]
    const float* __restrict__ dstTab,     // [N][8]
    const float* __restrict__ bs,         // [5]
    const int*   __restrict__ flag,
    float* __restrict__ out,
    int n_edges)
{
    const int e = blockIdx.x * 256 + threadIdx.x;
    if (e >= n_edges) return;

    const int stride = *flag;   // uniform scalar branch
    int src, dst;
    if (stride == 2) {
        src = eidx[2 * (size_t)e];
        dst = eidx[2 * ((size_t)n_edges + e)];
    } else {
        src = eidx[e];
        dst = eidx[(size_t)n_edges + e];
    }

    // issue all gathers + ew up-front
    const float4* __restrict__ ps = (const float4*)(srcTab + (size_t)src * 8);
    const float4* __restrict__ pd = (const float4*)(dstTab + (size_t)dst * 8);
    float4 a0 = ps[0], a1 = ps[1];
    float4 c0 = pd[0], c1 = pd[1];
    float w = ew[e];

    out[e] = w * edge_score(a0, a1, c0, c1,
                            attn_b[0], attn_b[1], attn_b[2], attn_b[3], attn_b[4],
                            bs[0], bs[1], bs[2], bs[3], bs[4], scorer_b[0]);
}

// ---------------------------------------------------------------------------
extern "C" void kernel_launch(void* const* d_in, const int* in_sizes, int n_in,
                              void* d_out, int out_size, void* d_ws, size_t ws_size,
                              hipStream_t stream) {
    const float* x        = (const float*)d_in[0];
    const int*   eidx     = (const int*)  d_in[1];
    const float* ew       = (const float*)d_in[2];
    const float* bases    = (const float*)d_in[3];
    const float* attn_w   = (const float*)d_in[4];
    const float* attn_b   = (const float*)d_in[5];
    const float* scorer_w = (const float*)d_in[6];
    const float* scorer_b = (const float*)d_in[7];
    float* out = (float*)d_out;

    const int n_nodes = in_sizes[0] / IN_DIM;
    const int n_edges = in_sizes[2];

    // workspace layout
    int*   flag   = (int*)d_ws;                            // offset 0
    float* bs     = (float*)d_ws + 16;                     // offset 64 B
    float* srcTab = (float*)d_ws + 64;                     // [N][8]
    float* dstTab = srcTab + (size_t)n_nodes * 8;          // [N][8]

    const int pblocks = (n_nodes + 127) / 128;
    proj_prep_kernel<<<pblocks + 1, 256, 0, stream>>>(
        x, attn_w, scorer_w, bases, eidx, srcTab, dstTab, bs, flag, n_nodes);

    const int eblocks = (n_edges + 255) / 256;
    edge_kernel<<<eblocks, 256, 0, stream>>>(
        eidx, ew, attn_b, scorer_b, srcTab, dstTab, bs, flag, out, n_edges);
}